// Round 3
// baseline (696.414 us; speedup 1.0000x reference)
//
#include <hip/hip_runtime.h>

// B=32768 rows, C=4096 cols, f32.
// Kernel 1: one wave per row. Row lives in 16 x float4 registers (single HBM read).
//   pass1: max+argmax, pass2: sum exp(v-m). Lane 0 writes ce*w to ws[row].
// Kernel 2: one block reduces 32768 partials -> mean -> d_out[0].

#define NROWS 32768
#define NCOLS 4096

__global__ __launch_bounds__(256) void wl_rows_kernel(
    const float* __restrict__ logits,
    const int* __restrict__ target,
    const float* __restrict__ weights,
    float* __restrict__ partial) {
  const int wave = threadIdx.x >> 6;
  const int lane = threadIdx.x & 63;
  const int row = blockIdx.x * 4 + wave;
  const float* rowp = logits + (size_t)row * NCOLS;

  // ---- load entire row: 64 lanes x 16 float4 = 4096 floats, coalesced ----
  float4 v[16];
#pragma unroll
  for (int it = 0; it < 16; ++it) {
    v[it] = *reinterpret_cast<const float4*>(rowp + it * 256 + lane * 4);
  }

  // ---- pass 1: lane-local max + argmax (indices ascend -> strict '>' keeps first) ----
  float bv = v[0].x;
  int bi = lane * 4;
#pragma unroll
  for (int it = 0; it < 16; ++it) {
    const int base = it * 256 + lane * 4;
    if (v[it].x > bv) { bv = v[it].x; bi = base + 0; }
    if (v[it].y > bv) { bv = v[it].y; bi = base + 1; }
    if (v[it].z > bv) { bv = v[it].z; bi = base + 2; }
    if (v[it].w > bv) { bv = v[it].w; bi = base + 3; }
  }

  // ---- wave reduce (max, argmax with first-index tiebreak) ----
#pragma unroll
  for (int off = 32; off > 0; off >>= 1) {
    float ov = __shfl_xor(bv, off, 64);
    int oi = __shfl_xor(bi, off, 64);
    if (ov > bv || (ov == bv && oi < bi)) { bv = ov; bi = oi; }
  }
  // all lanes now hold m = bv (row max), pred = bi (argmax)

  // ---- pass 2: sum of exp(v - m) ----
  float s = 0.f;
#pragma unroll
  for (int it = 0; it < 16; ++it) {
    s += __expf(v[it].x - bv);
    s += __expf(v[it].y - bv);
    s += __expf(v[it].z - bv);
    s += __expf(v[it].w - bv);
  }
#pragma unroll
  for (int off = 32; off > 0; off >>= 1) {
    s += __shfl_xor(s, off, 64);
  }

  // ---- lane 0: ce = m + log(sumexp) - x_t ; w = weights[t][pred] ----
  if (lane == 0) {
    const int t = target[row];
    const float xt = rowp[t];                              // L2/L3 hit (just streamed)
    const float w = weights[(size_t)t * NCOLS + bi];
    const float ce = bv + __logf(s) - xt;
    partial[row] = ce * w;
  }
}

__global__ __launch_bounds__(1024) void wl_reduce_kernel(
    const float* __restrict__ partial, float* __restrict__ out) {
  __shared__ float wsum[16];
  const int tid = threadIdx.x;
  float s = 0.f;
  const float4* p4 = reinterpret_cast<const float4*>(partial);
#pragma unroll
  for (int i = 0; i < 8; ++i) {  // 8192 float4 total / 1024 threads
    float4 p = p4[tid + i * 1024];
    s += p.x + p.y + p.z + p.w;
  }
#pragma unroll
  for (int off = 32; off > 0; off >>= 1) s += __shfl_xor(s, off, 64);
  if ((tid & 63) == 0) wsum[tid >> 6] = s;
  __syncthreads();
  if (tid < 16) {
    s = wsum[tid];
#pragma unroll
    for (int off = 8; off > 0; off >>= 1) s += __shfl_xor(s, off, 64);
    if (tid == 0) out[0] = s * (1.0f / NROWS);
  }
}

extern "C" void kernel_launch(void* const* d_in, const int* in_sizes, int n_in,
                              void* d_out, int out_size, void* d_ws, size_t ws_size,
                              hipStream_t stream) {
  const float* logits = (const float*)d_in[0];
  const int* target = (const int*)d_in[1];
  const float* weights = (const float*)d_in[2];
  float* partial = (float*)d_ws;  // 32768 floats = 128 KiB
  float* out = (float*)d_out;

  wl_rows_kernel<<<NROWS / 4, 256, 0, stream>>>(logits, target, weights, partial);
  wl_reduce_kernel<<<1, 1024, 0, stream>>>(partial, out);
}

// Round 7
// 676.248 us; speedup vs baseline: 1.0298x; 1.0298x over previous
//
#include <hip/hip_runtime.h>

// B=32768 rows, C=4096 cols, f32.
// Kernel 1: one wave per row. Row streamed once via non-temporal float4 loads
//   into 16x4 registers. x_t extracted in-register during the stream (t is
//   wave-uniform -> compile-time-indexed predicated selects + one shfl).
//   pass1: max+argmax (registers), pass2: sum exp(v-m) (registers).
//   Lane 0 writes ce*w to ws[row].
// Kernel 2: one block reduces 32768 partials -> mean -> d_out[0].

#define NROWS 32768
#define NCOLS 4096

typedef float f32x4 __attribute__((ext_vector_type(4)));

__global__ __launch_bounds__(256) void wl_rows_kernel(
    const float* __restrict__ logits,
    const int* __restrict__ target,
    const float* __restrict__ weights,
    float* __restrict__ partial) {
  const int wave = threadIdx.x >> 6;
  const int lane = threadIdx.x & 63;
  const int row = blockIdx.x * 4 + wave;
  const float* rowp = logits + (size_t)row * NCOLS;

  const int t = target[row];       // wave-uniform
  const int tchunk = t >> 2;       // which float4 chunk of the row holds x_t
  const int tlane = tchunk & 63;   // which lane loads that chunk
  const int tit = tchunk >> 6;     // at which iteration
  const int tcomp = t & 3;         // which component

  // ---- load entire row: 64 lanes x 16 float4 = 4096 floats, coalesced, NT ----
  f32x4 v[16];
#pragma unroll
  for (int it = 0; it < 16; ++it) {
    v[it] = __builtin_nontemporal_load(
        reinterpret_cast<const f32x4*>(rowp + it * 256 + lane * 4));
  }

  // ---- extract x_t in-register (it==tit is wave-uniform; compile-time index) ----
  float cand = 0.f;
#pragma unroll
  for (int it = 0; it < 16; ++it) {
    if (it == tit) {
      const float a = (tcomp & 1) ? v[it].y : v[it].x;
      const float b = (tcomp & 1) ? v[it].w : v[it].z;
      cand = (tcomp & 2) ? b : a;
    }
  }
  const float xt = __shfl(cand, tlane, 64);  // broadcast from owning lane

  // ---- pass 1: lane-local max + argmax (indices ascend -> strict '>' keeps first) ----
  float bv = v[0].x;
  int bi = lane * 4;
#pragma unroll
  for (int it = 0; it < 16; ++it) {
    const int base = it * 256 + lane * 4;
    if (v[it].x > bv) { bv = v[it].x; bi = base + 0; }
    if (v[it].y > bv) { bv = v[it].y; bi = base + 1; }
    if (v[it].z > bv) { bv = v[it].z; bi = base + 2; }
    if (v[it].w > bv) { bv = v[it].w; bi = base + 3; }
  }

  // ---- wave reduce (max, argmax with first-index tiebreak) ----
#pragma unroll
  for (int off = 32; off > 0; off >>= 1) {
    float ov = __shfl_xor(bv, off, 64);
    int oi = __shfl_xor(bi, off, 64);
    if (ov > bv || (ov == bv && oi < bi)) { bv = ov; bi = oi; }
  }
  // all lanes now hold m = bv (row max), pred = bi (argmax)

  // ---- pass 2: sum of exp(v - m) ----
  float s = 0.f;
#pragma unroll
  for (int it = 0; it < 16; ++it) {
    s += __expf(v[it].x - bv);
    s += __expf(v[it].y - bv);
    s += __expf(v[it].z - bv);
    s += __expf(v[it].w - bv);
  }
#pragma unroll
  for (int off = 32; off > 0; off >>= 1) {
    s += __shfl_xor(s, off, 64);
  }

  // ---- lane 0: ce = m + log(sumexp) - x_t ; w = weights[t][pred] ----
  if (lane == 0) {
    const float w = weights[(size_t)t * NCOLS + bi];
    const float ce = bv + __logf(s) - xt;
    partial[row] = ce * w;
  }
}

__global__ __launch_bounds__(1024) void wl_reduce_kernel(
    const float* __restrict__ partial, float* __restrict__ out) {
  __shared__ float wsum[16];
  const int tid = threadIdx.x;
  float s = 0.f;
  const f32x4* p4 = reinterpret_cast<const f32x4*>(partial);
#pragma unroll
  for (int i = 0; i < 8; ++i) {  // 8192 float4 total / 1024 threads
    f32x4 p = p4[tid + i * 1024];
    s += p.x + p.y + p.z + p.w;
  }
#pragma unroll
  for (int off = 32; off > 0; off >>= 1) s += __shfl_xor(s, off, 64);
  if ((tid & 63) == 0) wsum[tid >> 6] = s;
  __syncthreads();
  if (tid < 16) {
    s = wsum[tid];
#pragma unroll
    for (int off = 8; off > 0; off >>= 1) s += __shfl_xor(s, off, 64);
    if (tid == 0) out[0] = s * (1.0f / NROWS);
  }
}

extern "C" void kernel_launch(void* const* d_in, const int* in_sizes, int n_in,
                              void* d_out, int out_size, void* d_ws, size_t ws_size,
                              hipStream_t stream) {
  const float* logits = (const float*)d_in[0];
  const int* target = (const int*)d_in[1];
  const float* weights = (const float*)d_in[2];
  float* partial = (float*)d_ws;  // 32768 floats = 128 KiB
  float* out = (float*)d_out;

  wl_rows_kernel<<<NROWS / 4, 256, 0, stream>>>(logits, target, weights, partial);
  wl_reduce_kernel<<<1, 1024, 0, stream>>>(partial, out);
}